// Round 15
// baseline (1993.624 us; speedup 1.0000x reference)
//
#include <hip/hip_runtime.h>
#include <math.h>

#define D_MODEL  4096
#define D_HIDDEN 32768
#define BATCH    2048
#define KSEL     128
#define NDEAD    2048
#define TIECAP   256

#define NB_SEL 2048
#define NB_AG  2048
#define NB_AB  8192
#define NB_WD  8192
#define NB_MM  128            // aux mm256 blocks inside comboB
#define NB_WPREP 16384        // (D_MODEL/128) * (D_HIDDEN/64)

typedef short s16x8 __attribute__((ext_vector_type(8)));
typedef float f32x4 __attribute__((ext_vector_type(4)));

// -------------------- helpers --------------------
__device__ __forceinline__ unsigned int fkey(float f) {
    unsigned int u = __float_as_uint(f);
    return (u & 0x80000000u) ? ~u : (u | 0x80000000u);
}
__device__ __forceinline__ unsigned short f2bf(float f) {  // RTNE
    unsigned int u = __float_as_uint(f);
    u += 0x7FFFu + ((u >> 16) & 1u);
    return (unsigned short)(u >> 16);
}
__device__ __forceinline__ float bf2f(unsigned short h) {
    return __uint_as_float(((unsigned int)h) << 16);
}
// per-16-bit-lane order-preserving key transform (packed pair)
__device__ __forceinline__ unsigned int key16x2(unsigned int u) {
    const unsigned int s = (u >> 15) & 0x10001u;
    const unsigned int mask = s * 0xFFFFu;
    return (u ^ mask) | (~mask & 0x80008000u);
}
__device__ __forceinline__ float unkey16(unsigned int k) {  // 16-bit key -> float
    const unsigned int u = (k & 0x8000u) ? (k & 0x7FFFu) : (~k & 0xFFFFu);
    return __uint_as_float(u << 16);
}
__device__ __forceinline__ void async_copy16(void* lds_dst, const void* gsrc) {
    __builtin_amdgcn_global_load_lds(
        (const __attribute__((address_space(1))) unsigned int*)gsrc,
        (__attribute__((address_space(3))) unsigned int*)lds_dst,
        16, 0, 0);
}

// ==== prepw: [rows 0..BATCH-1: LN+Ahp+Dekker | BATCH: dead scan | rest: wprep] ====
// wprep tiles: 128(k) x 64(n) per block; writes 256B bf16 / 512B fp32 contiguous
// chunks per n-row. Per-element math identical to the old 32x32 version.
__global__ __launch_bounds__(256) void prepw_kernel(
    const float* __restrict__ x, const float* __restrict__ b_pre,
    double* __restrict__ mu, double* __restrict__ stdv, double* __restrict__ sinv,
    unsigned short* __restrict__ Ahp, float* __restrict__ xch, float* __restrict__ xcl,
    const unsigned char* __restrict__ mask8, int* __restrict__ dead_idx,
    int* __restrict__ dead_cnt, const int* __restrict__ num_dead_in,
    float* __restrict__ out_last,
    const float* __restrict__ w_enc, unsigned short* __restrict__ Bhp,
    float* __restrict__ wT, const int do_w)
{
    const int b = blockIdx.x;
    const int tid = threadIdx.x;
    __shared__ double red[4];
    __shared__ double sh_mu, sh_si;
    __shared__ float tt[64][129];     // 33 KB transpose buffer

    if (b > BATCH) {
        // ---------------- wprep tile: 128k x 64n ----------------
        const int wb = b - (BATCH + 1);
        const int bk0 = (wb & 31) * 128;        // D_MODEL/128 = 32 (x fastest)
        const int bn0 = (wb >> 5) * 64;
        // load: 8 iters x 16 k-rows; 16 lanes x float4 per k-row (256B chunks)
        const int n0 = (tid & 15) * 4;
#pragma unroll
        for (int it = 0; it < 8; ++it) {
            const int k = it * 16 + (tid >> 4);
            const float4 v = *(const float4*)(w_enc + (size_t)(bk0 + k) * D_HIDDEN + bn0 + n0);
            tt[n0 + 0][k] = v.x; tt[n0 + 1][k] = v.y;
            tt[n0 + 2][k] = v.z; tt[n0 + 3][k] = v.w;
        }
        __syncthreads();
        // store: thread -> (n = tid>>2, k0 = (tid&3)*32), 32 k each
        const int n = tid >> 2;
        const int k0 = (tid & 3) * 32;
        unsigned short* bp = Bhp + (size_t)(bn0 + n) * D_MODEL + bk0 + k0;
        float* wp = wT + (size_t)(bn0 + n) * D_MODEL + bk0 + k0;
#pragma unroll
        for (int j = 0; j < 32; j += 8) {
            float f[8];
#pragma unroll
            for (int e = 0; e < 8; ++e) f[e] = tt[n][k0 + j + e];
            uint4 ob;
            ob.x = (unsigned)f2bf(f[0]) | ((unsigned)f2bf(f[1]) << 16);
            ob.y = (unsigned)f2bf(f[2]) | ((unsigned)f2bf(f[3]) << 16);
            ob.z = (unsigned)f2bf(f[4]) | ((unsigned)f2bf(f[5]) << 16);
            ob.w = (unsigned)f2bf(f[6]) | ((unsigned)f2bf(f[7]) << 16);
            *(uint4*)(bp + j) = ob;
            if (do_w) {
                *(float4*)(wp + j)     = make_float4(f[0], f[1], f[2], f[3]);
                *(float4*)(wp + j + 4) = make_float4(f[4], f[5], f[6], f[7]);
            }
        }
        return;
    }
    if (b == BATCH) {
        // ---------------- dead-mask scan (wave 0) ----------------
        if (tid >= 64) return;
        const int lane = tid;
        int c = 0;
        for (int j = lane; j < D_HIDDEN; j += 64) c += (mask8[j] != 0);
#pragma unroll
        for (int off = 32; off > 0; off >>= 1) c += __shfl_down(c, off, 64);
        const int total_u8 = __shfl(c, 0, 64);
        const bool u8mode = (total_u8 == NDEAD);
        const int* mask32 = (const int*)mask8;
        int cnt = 0;
        for (int base = 0; base < D_HIDDEN; base += 64) {
            const int j = base + lane;
            const bool d = u8mode ? (mask8[j] != 0) : (mask32[j] != 0);
            const unsigned long long bm = __ballot(d);
            const int pre = __popcll(bm & ((1ull << lane) - 1ull));
            if (d && (cnt + pre) < NDEAD) dead_idx[cnt + pre] = j;
            cnt += __popcll(bm);
        }
        const int cc = cnt > NDEAD ? NDEAD : cnt;
        if (lane == 0) {
            *dead_cnt = cc;
            *out_last = (float)(*num_dead_in);
        }
        for (int t = cc + lane; t < NDEAD; t += 64) dead_idx[t] = 0;
        return;
    }
    // ---------------- prep row (identical math) ----------------
    const int row = b;
    const float* xr = x + (size_t)row * D_MODEL;
    float xv[16];
#pragma unroll
    for (int i = 0; i < 16; ++i) xv[i] = xr[tid + 256 * i];
    double s = 0.0;
#pragma unroll
    for (int i = 0; i < 16; ++i) s += (double)xv[i];
    const int lane = tid & 63, wid = tid >> 6;
#pragma unroll
    for (int off = 32; off > 0; off >>= 1) s += __shfl_down(s, off, 64);
    if (lane == 0) red[wid] = s;
    __syncthreads();
    if (tid == 0) sh_mu = (red[0] + red[1] + red[2] + red[3]) / (double)D_MODEL;
    __syncthreads();
    const double m = sh_mu;
    double s2 = 0.0;
#pragma unroll
    for (int i = 0; i < 16; ++i) { double d = (double)xv[i] - m; s2 += d * d; }
#pragma unroll
    for (int off = 32; off > 0; off >>= 1) s2 += __shfl_down(s2, off, 64);
    __syncthreads();
    if (lane == 0) red[wid] = s2;
    __syncthreads();
    if (tid == 0) {
        double var = (red[0] + red[1] + red[2] + red[3]) / (double)(D_MODEL - 1);
        double sd = sqrt(var);
        mu[row] = m;
        stdv[row] = sd;
        const double si = 1.0 / (sd + 1e-5);
        sinv[row] = si;
        sh_si = si;
    }
    __syncthreads();
    const double si = sh_si;
#pragma unroll
    for (int i = 0; i < 4; ++i) {
        const int j = (i * 256 + tid) * 4;
        const float4 x4 = *(const float4*)(xr + j);
        const float4 bp = *(const float4*)(b_pre + j);
        float vf[4], hi[4], lo[4];
        const float xe[4] = {x4.x, x4.y, x4.z, x4.w};
        const float be[4] = {bp.x, bp.y, bp.z, bp.w};
#pragma unroll
        for (int e = 0; e < 4; ++e) {
            const double t = ((double)xe[e] - m) * si;
            vf[e] = (float)t - be[e];
            const double a = t - (double)be[e];
            hi[e] = (float)a;
            lo[e] = (float)(a - (double)hi[e]);
        }
        uint2 hw;
        hw.x = (unsigned)f2bf(vf[0]) | ((unsigned)f2bf(vf[1]) << 16);
        hw.y = (unsigned)f2bf(vf[2]) | ((unsigned)f2bf(vf[3]) << 16);
        *(uint2*)(Ahp + (size_t)row * D_MODEL + j) = hw;
        *(float4*)(xch + (size_t)row * D_MODEL + j) = make_float4(hi[0], hi[1], hi[2], hi[3]);
        *(float4*)(xcl + (size_t)row * D_MODEL + j) = make_float4(lo[0], lo[1], lo[2], lo[3]);
    }
}

// -------------------- bsplit (fallback) --------------------
__global__ __launch_bounds__(256) void bsplit_kernel(
    const float* __restrict__ w_enc, unsigned short* __restrict__ Bhp)
{
    __shared__ float t[32][33];
    const int bk = blockIdx.x * 32;
    const int bn = blockIdx.y * 32;
    const int tid = threadIdx.x;
    const int lr = tid >> 3, lc4 = (tid & 7) * 4;
    const float4 v = *(const float4*)(w_enc + (size_t)(bk + lr) * D_HIDDEN + bn + lc4);
    t[lr][lc4 + 0] = v.x; t[lr][lc4 + 1] = v.y; t[lr][lc4 + 2] = v.z; t[lr][lc4 + 3] = v.w;
    __syncthreads();
    float o[4];
#pragma unroll
    for (int j = 0; j < 4; ++j) o[j] = t[lc4 + j][lr];
    uint2 hw;
    hw.x = (unsigned)f2bf(o[0]) | ((unsigned)f2bf(o[1]) << 16);
    hw.y = (unsigned)f2bf(o[2]) | ((unsigned)f2bf(o[3]) << 16);
    *(uint2*)(Bhp + (size_t)(bn + lr) * D_MODEL + bk + lc4) = hw;
}

// -------------------- wencT (fallback) --------------------
__global__ __launch_bounds__(256) void wencT_kernel(
    const float* __restrict__ w_enc, float* __restrict__ wT)
{
    __shared__ float t[32][33];
    const int bk = blockIdx.x * 32;
    const int bn = blockIdx.y * 32;
    const int tid = threadIdx.x;
    const int lr = tid >> 3, lc4 = (tid & 7) * 4;
    const float4 v = *(const float4*)(w_enc + (size_t)(bk + lr) * D_HIDDEN + bn + lc4);
    t[lr][lc4 + 0] = v.x; t[lr][lc4 + 1] = v.y; t[lr][lc4 + 2] = v.z; t[lr][lc4 + 3] = v.w;
    __syncthreads();
    const int j = tid >> 3, i4 = (tid & 7) * 4;
    float4 o;
    o.x = t[i4 + 0][j]; o.y = t[i4 + 1][j]; o.z = t[i4 + 2][j]; o.w = t[i4 + 3][j];
    *(float4*)(wT + (size_t)(bn + j) * D_MODEL + bk + i4) = o;
}

// ======== 256x256 bf16 MFMA GEMM, BK=64, 8 waves, 4-phase/K-tile, half-tile pipe ====
template<int EPI>
__global__ __launch_bounds__(512) void mm256_kernel(
    const unsigned short* __restrict__ A, const unsigned short* __restrict__ B,
    const int kdim, const int ntiles_x,
    const float* __restrict__ bias_n,
    const double* __restrict__ muv, const double* __restrict__ stdvv,
    void* __restrict__ outp, const long ostride)
{
    __shared__ unsigned short lds[2 * 4 * 8192];   // 128 KB: 2 bufs x 4 subplanes
    const int tid = threadIdx.x;
    const int lane = tid & 63, wid = tid >> 6;     // 8 waves
    const int cpx = gridDim.x >> 3;                // XCD swizzle (grid % 8 == 0)
    const int orig = blockIdx.x;
    const int wg = (orig & 7) * cpx + (orig >> 3);
    const int m0 = (wg % ntiles_x) * 256;
    const int n0 = (wg / ntiles_x) * 256;
    const int wm = (wid >> 2) * 128;               // 2 M-halves
    const int wn = (wid & 3) * 64;                 // 4 N-quarters
    const int fr = lane & 15, kq = lane >> 4;
    const int swr = (fr >> 1) & 3;                 // read-side quad XOR
    const int qg = (lane & 3) ^ ((lane >> 3) & 3); // write-side source quad
    const int qo = (kq ^ swr) * 8;

    f32x4 acc[8][4];
#pragma unroll
    for (int i = 0; i < 8; ++i)
#pragma unroll
        for (int j = 0; j < 4; ++j) acc[i][j] = (f32x4){0.f, 0.f, 0.f, 0.f};

    const unsigned short* sH0[4];
    int dH0[4];
#pragma unroll
    for (int j = 0; j < 4; ++j) {
        const int g = wid * 4 + j;
        const int is_b = g >> 4;
        const int sr = g & 15;
        const unsigned short* gp = is_b ? B : A;
        const int t0 = is_b ? n0 : m0;
        sH0[j] = gp + (size_t)(t0 + sr * 16 + (lane >> 2)) * kdim + qg * 8;
        dH0[j] = (is_b ? 2 : 0) * 8192 + sr * 512;
    }

    const int NT = kdim >> 6;
#pragma unroll
    for (int j = 0; j < 4; ++j) async_copy16(lds + dH0[j], sH0[j]);
#pragma unroll
    for (int j = 0; j < 4; ++j) async_copy16(lds + 8192 + dH0[j], sH0[j] + 32);
    if (NT > 1) {
#pragma unroll
        for (int j = 0; j < 4; ++j) async_copy16(lds + 32768 + dH0[j], sH0[j] + 64);
    }

    for (int t = 0; t < NT; ++t) {
        const int cur = t & 1;
        unsigned short* bb = (unsigned short*)lds + cur * 32768;
        unsigned short* nb = (unsigned short*)lds + (cur ^ 1) * 32768;
        const int k1 = (t + 1) << 6;
        const int k2 = (t + 2) << 6;

        if (t < NT - 1) { asm volatile("s_waitcnt vmcnt(8)" ::: "memory"); }
        else            { asm volatile("s_waitcnt vmcnt(4)" ::: "memory"); }
        asm volatile("s_barrier" ::: "memory");
        __builtin_amdgcn_sched_barrier(0);
        {
            if (t + 1 < NT) {
                async_copy16(nb + 8192 + dH0[0], sH0[0] + k1 + 32);
                async_copy16(nb + 8192 + dH0[1], sH0[1] + k1 + 32);
            }
            s16x8 a[4], b[4];
#pragma unroll
            for (int mi = 0; mi < 4; ++mi)
                a[mi] = *(const s16x8*)(bb + (wm + mi * 16 + fr) * 32 + qo);
#pragma unroll
            for (int ni = 0; ni < 4; ++ni)
                b[ni] = *(const s16x8*)(bb + 2 * 8192 + (wn + ni * 16 + fr) * 32 + qo);
            __builtin_amdgcn_s_setprio(1);
#pragma unroll
            for (int mi = 0; mi < 4; ++mi)
#pragma unroll
                for (int ni = 0; ni < 4; ++ni)
                    acc[mi][ni] = __builtin_amdgcn_mfma_f32_16x16x32_bf16(a[mi], b[ni], acc[mi][ni], 0, 0, 0);
            __builtin_amdgcn_s_setprio(0);
            asm volatile("s_barrier" ::: "memory");
            __builtin_amdgcn_sched_barrier(0);
            if (t + 1 < NT) {
                async_copy16(nb + 8192 + dH0[2], sH0[2] + k1 + 32);
                async_copy16(nb + 8192 + dH0[3], sH0[3] + k1 + 32);
            }
            s16x8 a2[4];
#pragma unroll
            for (int mi = 0; mi < 4; ++mi)
                a2[mi] = *(const s16x8*)(bb + (wm + (mi + 4) * 16 + fr) * 32 + qo);
            __builtin_amdgcn_s_setprio(1);
#pragma unroll
            for (int mi = 0; mi < 4; ++mi)
#pragma unroll
                for (int ni = 0; ni < 4; ++ni)
                    acc[mi + 4][ni] = __builtin_amdgcn_mfma_f32_16x16x32_bf16(a2[mi], b[ni], acc[mi + 4][ni], 0, 0, 0);
            __builtin_amdgcn_s_setprio(0);
        }
        if (t < NT - 1) { asm volatile("s_waitcnt vmcnt(8)" ::: "memory"); }
        else            { asm volatile("s_waitcnt vmcnt(0)" ::: "memory"); }
        asm volatile("s_barrier" ::: "memory");
        __builtin_amdgcn_sched_barrier(0);
        {
            if (t + 2 < NT) {
                async_copy16(bb + dH0[0], sH0[0] + k2);
                async_copy16(bb + dH0[1], sH0[1] + k2);
            }
            s16x8 a[4], b[4];
#pragma unroll
            for (int mi = 0; mi < 4; ++mi)
                a[mi] = *(const s16x8*)(bb + 8192 + (wm + mi * 16 + fr) * 32 + qo);
#pragma unroll
            for (int ni = 0; ni < 4; ++ni)
                b[ni] = *(const s16x8*)(bb + 3 * 8192 + (wn + ni * 16 + fr) * 32 + qo);
            __builtin_amdgcn_s_setprio(1);
#pragma unroll
            for (int mi = 0; mi < 4; ++mi)
#pragma unroll
                for (int ni = 0; ni < 4; ++ni)
                    acc[mi][ni] = __builtin_amdgcn_mfma_f32_16x16x32_bf16(a[mi], b[ni], acc[mi][ni], 0, 0, 0);
            __builtin_amdgcn_s_setprio(0);
            asm volatile("s_barrier" ::: "memory");
            __builtin_amdgcn_sched_barrier(0);
            if (t + 2 < NT) {
                async_copy16(bb + dH0[2], sH0[2] + k2);
                async_copy16(bb + dH0[3], sH0[3] + k2);
            }
            s16x8 a2[4];
#pragma unroll
            for (int mi = 0; mi < 4; ++mi)
                a2[mi] = *(const s16x8*)(bb + 8192 + (wm + (mi + 4) * 16 + fr) * 32 + qo);
            __builtin_amdgcn_s_setprio(1);
#pragma unroll
            for (int mi = 0; mi < 4; ++mi)
#pragma unroll
                for (int ni = 0; ni < 4; ++ni)
                    acc[mi + 4][ni] = __builtin_amdgcn_mfma_f32_16x16x32_bf16(a2[mi], b[ni], acc[mi + 4][ni], 0, 0, 0);
            __builtin_amdgcn_s_setprio(0);
        }
    }

#pragma unroll
    for (int ni = 0; ni < 4; ++ni) {
        const int col = n0 + wn + ni * 16 + fr;
        const float be = bias_n[col];
#pragma unroll
        for (int mi = 0; mi < 8; ++mi) {
            const int rb = m0 + wm + mi * 16 + kq * 4;
            if (EPI == 0) {
                unsigned short* O = (unsigned short*)outp;
#pragma unroll
                for (int r = 0; r < 4; ++r)
                    O[(size_t)(rb + r) * ostride + col] = f2bf(acc[mi][ni][r] + be);
            } else {
                float* O = (float*)outp;
#pragma unroll
                for (int r = 0; r < 4; ++r) {
                    const int m = rb + r;
                    O[(size_t)m * ostride + col] =
                        (acc[mi][ni][r] + be) * (float)stdvv[m] + (float)muv[m];
                }
            }
        }
    }
}

// ======= comboA: [sel | auxg | auxb(nb_ab) | wdec2bf(nb_wd)] in one launch =======
__global__ __launch_bounds__(256) void comboA_kernel(
    const unsigned short* __restrict__ p16,
    int* __restrict__ topk_idx, float* __restrict__ topk_val,
    int* __restrict__ sure_cnt, int* __restrict__ tie_cnt, int* __restrict__ cand_col,
    const int* __restrict__ dead_idx, const int* __restrict__ dead_cnt,
    unsigned short* __restrict__ Ahd,
    const float* __restrict__ w_dec, unsigned short* __restrict__ Bhd,
    unsigned short* __restrict__ wd16,
    const int nb_ab, const int nb_wd)
{
    const int b = blockIdx.x;
    const int tid = threadIdx.x;
    __shared__ float tsm[32][33];
    __shared__ int red[4];
    __shared__ int sh_sel, sh_tie;

    if (b < NB_SEL) {
        const int row = b;
        const int lane = tid & 63, wid = tid >> 6;
        const unsigned short* pr = p16 + (size_t)row * D_HIDDEN;
        uint4 kr[16];
#pragma unroll
        for (int i = 0; i < 16; ++i) {
            uint4 w = *(const uint4*)(pr + (i * 256 + tid) * 8);
            w.x = key16x2(w.x); w.y = key16x2(w.y); w.z = key16x2(w.z); w.w = key16x2(w.w);
            kr[i] = w;
        }
        if (tid == 0) { sh_sel = 0; sh_tie = 0; }
        unsigned int lo = 0, hi = 65535;
        while (lo < hi) {
            const unsigned int mid = (lo + hi) >> 1;
            int c = 0;
#pragma unroll
            for (int i = 0; i < 16; ++i) {
                const unsigned int u[4] = {kr[i].x, kr[i].y, kr[i].z, kr[i].w};
#pragma unroll
                for (int e = 0; e < 4; ++e) {
                    c += (int)((u[e] & 0xFFFFu) > mid);
                    c += (int)((u[e] >> 16) > mid);
                }
            }
#pragma unroll
            for (int off = 32; off > 0; off >>= 1) c += __shfl_down(c, off, 64);
            if (lane == 0) red[wid] = c;
            __syncthreads();
            const int total = red[0] + red[1] + red[2] + red[3];
            if (total < KSEL) hi = mid; else lo = mid + 1;
            __syncthreads();
        }
        const unsigned int K16 = lo;
        const float vc = unkey16(K16);
        const float DLT = 1.3e-2f;
        const float sureT = vc + 2.f * DLT;
        const float candT = vc - 2.f * DLT;
        const unsigned int sK = fkey(sureT) >> 16;
        const unsigned int cK = fkey(candT) >> 16;
        int* oidx = topk_idx + row * KSEL;
        float* oval = topk_val + row * KSEL;
        int* cc = cand_col + row * TIECAP;
#pragma unroll
        for (int i = 0; i < 16; ++i) {
            const int j0 = (i * 256 + tid) * 8;
            const unsigned int u[4] = {kr[i].x, kr[i].y, kr[i].z, kr[i].w};
#pragma unroll
            for (int e = 0; e < 8; ++e) {
                const unsigned int k = (e & 1) ? (u[e >> 1] >> 16) : (u[e >> 1] & 0xFFFFu);
                if (k < cK) continue;
                const float v = unkey16(k);
                if (k > sK && v > sureT) {
                    const int pos = atomicAdd(&sh_sel, 1);
                    oidx[pos] = j0 + e;
                    oval[pos] = v > 0.f ? v : 0.f;
                } else if (v >= candT) {
                    const int t = atomicAdd(&sh_tie, 1);
                    if (t < TIECAP) cc[t] = j0 + e;
                }
            }
        }
        __syncthreads();
        if (tid == 0) {
            sure_cnt[row] = sh_sel;
            tie_cnt[row] = sh_tie > TIECAP ? TIECAP : sh_tie;
        }
        return;
    }
    if (b < NB_SEL + NB_AG) {
        const int r = b - NB_SEL;
        const int dc = *dead_cnt;
#pragma unroll
        for (int i = 0; i < 8; ++i) {
            const int c = i * 256 + tid;
            unsigned short v = 0;
            if (c < dc) {
                const unsigned short u = p16[(size_t)r * D_HIDDEN + dead_idx[c]];
                v = (u & 0x8000u) ? (unsigned short)0 : u;
            }
            Ahd[(size_t)r * NDEAD + c] = v;
        }
        return;
    }
    if (b < NB_SEL + NB_AG + nb_ab) {
        const int idx = b - (NB_SEL + NB_AG);
        const int k0 = (idx & 63) * 32;
        const int n0 = (idx >> 6) * 32;
        const int i = tid >> 3, j4 = (tid & 7) * 4;
        const int srow = dead_idx[k0 + i];
        const float4 v = *(const float4*)(w_dec + (size_t)srow * D_MODEL + n0 + j4);
        tsm[i][j4 + 0] = v.x; tsm[i][j4 + 1] = v.y; tsm[i][j4 + 2] = v.z; tsm[i][j4 + 3] = v.w;
        __syncthreads();
        const int j = tid >> 3, i4 = (tid & 7) * 4;
        uint2 hw;
        hw.x = (unsigned)f2bf(tsm[i4 + 0][j]) | ((unsigned)f2bf(tsm[i4 + 1][j]) << 16);
        hw.y = (unsigned)f2bf(tsm[i4 + 2][j]) | ((unsigned)f2bf(tsm[i4 + 3][j]) << 16);
        *(uint2*)(Bhd + (size_t)(n0 + j) * NDEAD + k0 + i4) = hw;
        return;
    }
    {
        const int bb = b - (NB_SEL + NB_AG + nb_ab);
        (void)nb_wd;
        const size_t base0 = (size_t)bb * 16384;
#pragma unroll
        for (int it = 0; it < 8; ++it) {
            const size_t off = base0 + (size_t)it * 2048 + (size_t)tid * 8;
            const float4 a = *(const float4*)(w_dec + off);
            const float4 c = *(const float4*)(w_dec + off + 4);
            uint4 o;
            o.x = (unsigned)f2bf(a.x) | ((unsigned)f2bf(a.y) << 16);
            o.y = (unsigned)f2bf(a.z) | ((unsigned)f2bf(a.w) << 16);
            o.z = (unsigned)f2bf(c.x) | ((unsigned)f2bf(c.y) << 16);
            o.w = (unsigned)f2bf(c.z) | ((unsigned)f2bf(c.w) << 16);
            *(uint4*)(wd16 + off) = o;
        }
        return;
    }
}

// ---------- standalone auxb + wdec2bf (fallback ordering) ----------
__global__ __launch_bounds__(256) void auxb_kernel(
    const float* __restrict__ w_dec, const int* __restrict__ dead_idx,
    unsigned short* __restrict__ Bhd)
{
    __shared__ float t[32][33];
    const int k0 = blockIdx.x * 32;
    const int n0 = blockIdx.y * 32;
    const int tid = threadIdx.x;
    const int i = tid >> 3, j4 = (tid & 7) * 4;
    const int srow = dead_idx[k0 + i];
    const float4 v = *(const float4*)(w_dec + (size_t)srow * D_MODEL + n0 + j4);
    t[i][j4 + 0] = v.x; t[i][j4 + 1] = v.y; t[i][j4 + 2] = v.z; t[i][j4 + 3] = v.w;
    __syncthreads();
    const int j = tid >> 3, i4 = (tid & 7) * 4;
    uint2 hw;
    hw.x = (unsigned)f2bf(t[i4 + 0][j]) | ((unsigned)f2bf(t[i4 + 1][j]) << 16);
    hw.y = (unsigned)f2bf(t[i4 + 2][j]) | ((unsigned)f2bf(t[i4 + 3][j]) << 16);
    *(uint2*)(Bhd + (size_t)(n0 + j) * NDEAD + k0 + i4) = hw;
}

__global__ __launch_bounds__(256) void wdec2bf_kernel(
    const float* __restrict__ w_dec, unsigned short* __restrict__ wd16)
{
    const size_t gid = (size_t)blockIdx.x * 256 + threadIdx.x;
    const size_t base = gid * 8;
    const float4 a = *(const float4*)(w_dec + base);
    const float4 b = *(const float4*)(w_dec + base + 4);
    uint4 o;
    o.x = (unsigned)f2bf(a.x) | ((unsigned)f2bf(a.y) << 16);
    o.y = (unsigned)f2bf(a.z) | ((unsigned)f2bf(a.w) << 16);
    o.z = (unsigned)f2bf(b.x) | ((unsigned)f2bf(b.y) << 16);
    o.w = (unsigned)f2bf(b.z) | ((unsigned)f2bf(b.w) << 16);
    *(uint4*)(wd16 + base) = o;
}

// ======= comboB: [aux mm256 (nb_mm blocks) | row-refine (BATCH blocks)] =========
__global__ __launch_bounds__(512) void comboB_kernel(
    const unsigned short* __restrict__ A, const unsigned short* __restrict__ B,
    const float* __restrict__ bias_n,
    const double* __restrict__ muv, const double* __restrict__ stdvv,
    float* __restrict__ out1,
    const int* __restrict__ tie_cnt, const int* __restrict__ cand_col,
    double* __restrict__ cand_val,
    const float* __restrict__ xch, const float* __restrict__ xcl,
    const float* __restrict__ wT, const float* __restrict__ b_enc,
    const int nb_mm)
{
    __shared__ unsigned short lds[2 * 4 * 8192];   // 128 KB (refine uses first 32 KB)
    const int tid = threadIdx.x;
    const int lane = tid & 63, wid = tid >> 6;

    if (blockIdx.x >= nb_mm) {
        // ---------------- row refine ----------------
        const int row = blockIdx.x - nb_mm;
        const int T = tie_cnt[row];
        if (T == 0) return;
        float* shh = (float*)lds;
        float* shl = shh + D_MODEL;
        const float* hr = xch + (size_t)row * D_MODEL;
        const float* lr2 = xcl + (size_t)row * D_MODEL;
        {
            const int o = tid * 8;
            *(float4*)(shh + o)     = *(const float4*)(hr + o);
            *(float4*)(shh + o + 4) = *(const float4*)(hr + o + 4);
            *(float4*)(shl + o)     = *(const float4*)(lr2 + o);
            *(float4*)(shl + o + 4) = *(const float4*)(lr2 + o + 4);
        }
        __syncthreads();
        for (int slot = wid; slot < T; slot += 8) {
            const int col = cand_col[row * TIECAP + slot];
            const float* wr = wT + (size_t)col * D_MODEL;
            double s0 = 0.0, s1 = 0.0;
            for (int k = lane * 4; k < D_MODEL; k += 512) {
                {
                    const float4 h = *(const float4*)(shh + k);
                    const float4 l = *(const float4*)(shl + k);
                    const float4 w4 = *(const float4*)(wr + k);
                    s0 += ((double)h.x + (double)l.x) * (double)w4.x;
                    s0 += ((double)h.y + (double)l.y) * (double)w4.y;
                    s0 += ((double)h.z + (double)l.z) * (double)w4.z;
                    s0 += ((double)h.w + (double)l.w) * (double)w4.w;
                }
                {
                    const int k2 = k + 256;
                    const float4 h = *(const float4*)(shh + k2);
                    const float4 l = *(const float4*)(shl + k2);
                    const float4 w4 = *(const float4*)(wr + k2);
                    s1 += ((double)h.x + (double)l.x) * (double)w4.x;
                    s1 += ((double)h.y + (double)l.y) * (double)w4.y;
                    s1 += ((double)h.z + (double)l.z) * (double)w4.z;
                    s1 += ((double)h.w + (double)l.w) * (double)w4.w;
                }
            }
            double s = s0 + s1;
#pragma unroll
            for (int off = 32; off > 0; off >>= 1) s += __shfl_down(s, off, 64);
            if (lane == 0) cand_val[row * TIECAP + slot] = s + (double)b_enc[col];
        }
        return;
    }

    // ---------------- aux mm256 (EPI=1), K = NDEAD ----------------
    const int kdim = NDEAD;
    const int ntiles_x = BATCH / 256;
    const int cpx = nb_mm >> 3;
    const int orig = blockIdx.x;
    const int wg = (orig & 7) * cpx + (orig >> 3);
    const int m0 = (wg % ntiles_x) * 256;
    const int n0 = (wg / ntiles_x) * 256;
    const int wm = (wid >> 2) * 128;
    const int wn = (wid & 3) * 64;
    const int fr = lane & 15, kq = lane >> 4;
    const int swr = (fr >> 1) & 3;
    const int qg = (lane & 3) ^ ((lane >> 3) & 3);
    const int qo = (kq ^ swr) * 8;

    f32x4 acc[8][4];
#pragma unroll
    for (int i = 0; i < 8; ++i)
#pragma unroll
        for (int j = 0; j < 4; ++j) acc[i][j] = (f32x4){0.f, 0.f, 0.f, 0.f};

    const unsigned short* sH0[4];
    int dH0[4];
#pragma unroll
    for (int j = 0; j < 4; ++j) {
        const int g = wid * 4 + j;
        const int is_b = g >> 4;
        const int sr = g & 15;
        const unsigned short* gp = is_b ? B : A;
        const int t0 = is_b ? n0 : m0;
        sH0[j] = gp + (size_t)(t0 + sr * 16 + (lane >> 2)) * kdim + qg * 8;
        dH0[j] = (is_b ? 2 : 0) * 8192 + sr * 512;
    }

    const int NT = kdim >> 6;
#pragma unroll
    for (int j = 0; j < 4; ++j) async_copy16(lds + dH0[j], sH0[j]);
#pragma unroll
    for (int j = 0; j < 4; ++j) async_copy16(lds + 8192 + dH0[j], sH0[j] + 32);
    if (NT > 1) {
#pragma unroll
        for (int j = 0; j < 4; ++j) async_copy16(lds + 32768 + dH0[j], sH0[j] + 64);
    }

    for (int t = 0; t < NT; ++t) {
        const int cur = t & 1;
        unsigned short* bb = (unsigned short*)lds + cur * 32768;
        unsigned short* nb = (unsigned short*)lds + (cur ^ 1) * 32768;
        const int k1 = (t + 1) << 6;
        const int k2 = (t + 2) << 6;

        if (t < NT - 1) { asm volatile("s_waitcnt vmcnt(8)" ::: "memory"); }
        else            { asm volatile("s_waitcnt vmcnt(4)" ::: "memory"); }
        asm volatile("s_barrier" ::: "memory");
        __builtin_amdgcn_sched_barrier(0);
        {
            if (t + 1 < NT) {
                async_copy16(nb + 8192 + dH0[0], sH0[0] + k1 + 32);
                async_copy16(nb + 8192 + dH0[1], sH0[1] + k1 + 32);
            }
            s16x8 a[4], b[4];
#pragma unroll
            for (int mi = 0; mi < 4; ++mi)
                a[mi] = *(const s16x8*)(bb + (wm + mi * 16 + fr) * 32 + qo);
#pragma unroll
            for (int ni = 0; ni < 4; ++ni)
                b[ni] = *(const s16x8*)(bb + 2 * 8192 + (wn + ni * 16 + fr) * 32 + qo);
            __builtin_amdgcn_s_setprio(1);
#pragma unroll
            for (int mi = 0; mi < 4; ++mi)
#pragma unroll
                for (int ni = 0; ni < 4; ++ni)
                    acc[mi][ni] = __builtin_amdgcn_mfma_f32_16x16x32_bf16(a[mi], b[ni], acc[mi][ni], 0, 0, 0);
            __builtin_amdgcn_s_setprio(0);
            asm volatile("s_barrier" ::: "memory");
            __builtin_amdgcn_sched_barrier(0);
            if (t + 1 < NT) {
                async_copy16(nb + 8192 + dH0[2], sH0[2] + k1 + 32);
                async_copy16(nb + 8192 + dH0[3], sH0[3] + k1 + 32);
            }
            s16x8 a2[4];
#pragma unroll
            for (int mi = 0; mi < 4; ++mi)
                a2[mi] = *(const s16x8*)(bb + (wm + (mi + 4) * 16 + fr) * 32 + qo);
            __builtin_amdgcn_s_setprio(1);
#pragma unroll
            for (int mi = 0; mi < 4; ++mi)
#pragma unroll
                for (int ni = 0; ni < 4; ++ni)
                    acc[mi + 4][ni] = __builtin_amdgcn_mfma_f32_16x16x32_bf16(a2[mi], b[ni], acc[mi + 4][ni], 0, 0, 0);
            __builtin_amdgcn_s_setprio(0);
        }
        if (t < NT - 1) { asm volatile("s_waitcnt vmcnt(8)" ::: "memory"); }
        else            { asm volatile("s_waitcnt vmcnt(0)" ::: "memory"); }
        asm volatile("s_barrier" ::: "memory");
        __builtin_amdgcn_sched_barrier(0);
        {
            if (t + 2 < NT) {
                async_copy16(bb + dH0[0], sH0[0] + k2);
                async_copy16(bb + dH0[1], sH0[1] + k2);
            }
            s16x8 a[4], b[4];
#pragma unroll
            for (int mi = 0; mi < 4; ++mi)
                a[mi] = *(const s16x8*)(bb + 8192 + (wm + mi * 16 + fr) * 32 + qo);
#pragma unroll
            for (int ni = 0; ni < 4; ++ni)
                b[ni] = *(const s16x8*)(bb + 3 * 8192 + (wn + ni * 16 + fr) * 32 + qo);
            __builtin_amdgcn_s_setprio(1);
#pragma unroll
            for (int mi = 0; mi < 4; ++mi)
#pragma unroll
                for (int ni = 0; ni < 4; ++ni)
                    acc[mi][ni] = __builtin_amdgcn_mfma_f32_16x16x32_bf16(a[mi], b[ni], acc[mi][ni], 0, 0, 0);
            __builtin_amdgcn_s_setprio(0);
            asm volatile("s_barrier" ::: "memory");
            __builtin_amdgcn_sched_barrier(0);
            if (t + 2 < NT) {
                async_copy16(bb + dH0[2], sH0[2] + k2);
                async_copy16(bb + dH0[3], sH0[3] + k2);
            }
            s16x8 a2[4];
#pragma unroll
            for (int mi = 0; mi < 4; ++mi)
                a2[mi] = *(const s16x8*)(bb + 8192 + (wm + (mi + 4) * 16 + fr) * 32 + qo);
            __builtin_amdgcn_s_setprio(1);
#pragma unroll
            for (int mi = 0; mi < 4; ++mi)
#pragma unroll
                for (int ni = 0; ni < 4; ++ni)
                    acc[mi + 4][ni] = __builtin_amdgcn_mfma_f32_16x16x32_bf16(a2[mi], b[ni], acc[mi + 4][ni], 0, 0, 0);
            __builtin_amdgcn_s_setprio(0);
        }
    }

#pragma unroll
    for (int ni = 0; ni < 4; ++ni) {
        const int col = n0 + wn + ni * 16 + fr;
        const float be = bias_n[col];
#pragma unroll
        for (int mi = 0; mi < 8; ++mi) {
            const int rb = m0 + wm + mi * 16 + kq * 4;
#pragma unroll
            for (int r = 0; r < 4; ++r) {
                const int m = rb + r;
                out1[(size_t)m * D_MODEL + col] =
                    (acc[mi][ni][r] + be) * (float)stdvv[m] + (float)muv[m];
            }
        }
    }
}

// ---------- decode_fin: per-row candidate rank (fin) fused with sparse decode ----
__global__ __launch_bounds__(256) void decode_fin_kernel(
    const int* __restrict__ sure_cnt, const int* __restrict__ tie_cnt,
    const int* __restrict__ cand_col, const double* __restrict__ cand_val,
    const int* __restrict__ topk_idx, const float* __restrict__ topk_val,
    const unsigned short* __restrict__ wd16, const float* __restrict__ b_pre,
    const double* __restrict__ mu, const double* __restrict__ stdv,
    float* __restrict__ out0)
{
    const int row = blockIdx.x;
    const int tid = threadIdx.x;
    __shared__ double vals[TIECAP];
    __shared__ int cols[TIECAP];
    __shared__ int sidx[KSEL];
    __shared__ float sval[KSEL];
    const int G = sure_cnt[row];
    const int T = tie_cnt[row];
    const int R = KSEL - G;
    if (tid < T) {
        vals[tid] = cand_val[row * TIECAP + tid];
        cols[tid] = cand_col[row * TIECAP + tid];
    }
    if (tid < G) {
        sidx[tid] = topk_idx[row * KSEL + tid];
        sval[tid] = topk_val[row * KSEL + tid];
    }
    __syncthreads();
    if (tid < T) {
        const double v = vals[tid];
        const int c = cols[tid];
        int rank = 0;
        for (int u = 0; u < T; ++u) {
            const double vu = vals[u];
            rank += (int)((vu > v) || (vu == v && cols[u] < c));
        }
        if (rank < R) {
            sidx[G + rank] = c;
            sval[G + rank] = v > 0.0 ? (float)v : 0.f;
        }
    }
    const int take = R < T ? R : T;
    if (tid >= take && tid < R) {
        sidx[G + tid] = (T > 0) ? cols[0] : 0;
        sval[G + tid] = 0.f;
    }
    __syncthreads();
    float acc[16];
#pragma unroll
    for (int i = 0; i < 16; ++i) acc[i] = 0.f;
    const int dbase = tid * 16;
    for (int k = 0; k < KSEL; ++k) {
        const float v = sval[k];
        if (v == 0.f) continue;
        const uint4* wr = (const uint4*)(wd16 + (size_t)sidx[k] * D_MODEL + dbase);
        const uint4 w0 = wr[0], w1 = wr[1];
        const unsigned int u[8] = {w0.x, w0.y, w0.z, w0.w, w1.x, w1.y, w1.z, w1.w};
#pragma unroll
        for (int i = 0; i < 8; ++i) {
            acc[2 * i]     += v * __uint_as_float(u[i] << 16);
            acc[2 * i + 1] += v * __uint_as_float(u[i] & 0xFFFF0000u);
        }
    }
    const float st = (float)stdv[row];
    const float mm = (float)mu[row];
    float* o = out0 + (size_t)row * D_MODEL + dbase;
#pragma unroll
    for (int i = 0; i < 16; ++i) {
        o[i] = (acc[i] + b_pre[dbase + i]) * st + mm;
    }
}

// -------------------- launch --------------------
extern "C" void kernel_launch(void* const* d_in, const int* in_sizes, int n_in,
                              void* d_out, int out_size, void* d_ws, size_t ws_size,
                              hipStream_t stream)
{
    (void)in_sizes; (void)n_in; (void)out_size;
    const float* x      = (const float*)d_in[0];
    const float* w_enc  = (const float*)d_in[1];
    const float* w_dec  = (const float*)d_in[2];
    const float* b_enc  = (const float*)d_in[3];
    const float* b_pre  = (const float*)d_in[4];
    const unsigned char* dead_mask = (const unsigned char*)d_in[5];
    const int* num_dead = (const int*)d_in[6];
    float* out = (float*)d_out;

    char* base = (char*)d_ws;
    char* w = base;
    auto alloc = [&](size_t bytes) -> char* {
        char* p = w;
        w += (bytes + 255) & ~(size_t)255;
        return p;
    };
    unsigned short* p16 = (unsigned short*)alloc((size_t)BATCH * D_HIDDEN * 2); // 128 MB
    double* mu       = (double*)alloc((size_t)BATCH * 8);
    double* stdv     = (double*)alloc((size_t)BATCH * 8);
    double* sinv     = (double*)alloc((size_t)BATCH * 8);
    int* topk_idx    = (int*)alloc((size_t)BATCH * KSEL * 4);
    float* topk_val  = (float*)alloc((size_t)BATCH * KSEL * 4);
    int* dead_idx    = (int*)alloc((size_t)NDEAD * 4);
    int* dead_cnt    = (int*)alloc(256);
    int* sure_cnt    = (int*)alloc((size_t)BATCH * 4);
    int* tie_cnt     = (int*)alloc((size_t)BATCH * 4);
    int* cand_col    = (int*)alloc((size_t)BATCH * TIECAP * 4);      // 2 MB
    double* cand_val = (double*)alloc((size_t)BATCH * TIECAP * 8);   // 4 MB
    float* xch       = (float*)alloc((size_t)BATCH * D_MODEL * 4);   // 32 MB
    float* xcl       = (float*)alloc((size_t)BATCH * D_MODEL * 4);   // 32 MB
    unsigned short* Ahp = (unsigned short*)alloc((size_t)BATCH * D_MODEL * 2);    // 16 MB
    char* region     = alloc((size_t)D_HIDDEN * D_MODEL * 4);                     // 512 MB
    float* wT_big    = (float*)alloc((size_t)D_HIDDEN * D_MODEL * 4);             // 512 MB
    const size_t need_big = (size_t)(w - base);
    const bool bigws = (ws_size >= need_big);

    // time-multiplexed region:
    unsigned short* Bhp = (unsigned short*)region;                 // 256 MB, enc phase
    float* wT_small = (float*)region;                              // 512 MB (fallback, after enc)
    unsigned short* wd16 = (unsigned short*)region;                // 256 MB, decode phase
    unsigned short* Bhd  = (unsigned short*)(region + (size_t)D_HIDDEN * D_MODEL * 2); // 16 MB
    unsigned short* Ahd  = Ahp;                                    // 8 MB (Ahp dead after enc)
    float* wT = bigws ? wT_big : wT_small;

    float* out0 = out;                                   // recons
    float* out1 = out + (size_t)BATCH * D_MODEL;         // auxk
    float* out_last = out + (size_t)2 * BATCH * D_MODEL; // num_dead

    if (bigws) {
        prepw_kernel<<<BATCH + 1 + NB_WPREP, 256, 0, stream>>>(
            x, b_pre, mu, stdv, sinv, Ahp, xch, xcl,
            dead_mask, dead_idx, dead_cnt, num_dead, out_last,
            w_enc, Bhp, wT, 1);
        mm256_kernel<0><<<(BATCH / 256) * (D_HIDDEN / 256), 512, 0, stream>>>(
            Ahp, Bhp, D_MODEL, BATCH / 256, b_enc, nullptr, nullptr, p16, (long)D_HIDDEN);
        comboA_kernel<<<NB_SEL + NB_AG + NB_AB + NB_WD, 256, 0, stream>>>(
            p16, topk_idx, topk_val, sure_cnt, tie_cnt, cand_col,
            dead_idx, dead_cnt, Ahd, w_dec, Bhd, wd16, NB_AB, NB_WD);
        comboB_kernel<<<NB_MM + BATCH, 512, 0, stream>>>(
            Ahd, Bhd, b_pre, mu, stdv, out1,
            tie_cnt, cand_col, cand_val, xch, xcl, wT, b_enc, NB_MM);
    } else {
        prepw_kernel<<<BATCH + 1, 256, 0, stream>>>(
            x, b_pre, mu, stdv, sinv, Ahp, xch, xcl,
            dead_mask, dead_idx, dead_cnt, num_dead, out_last,
            w_enc, Bhp, nullptr, 0);
        bsplit_kernel<<<dim3(D_MODEL / 32, D_HIDDEN / 32), 256, 0, stream>>>(w_enc, Bhp);
        mm256_kernel<0><<<(BATCH / 256) * (D_HIDDEN / 256), 512, 0, stream>>>(
            Ahp, Bhp, D_MODEL, BATCH / 256, b_enc, nullptr, nullptr, p16, (long)D_HIDDEN);
        wencT_kernel<<<dim3(D_MODEL / 32, D_HIDDEN / 32), 256, 0, stream>>>(w_enc, wT);
        comboA_kernel<<<NB_SEL + NB_AG, 256, 0, stream>>>(
            p16, topk_idx, topk_val, sure_cnt, tie_cnt, cand_col,
            dead_idx, dead_cnt, Ahd, w_dec, Bhd, wd16, 0, 0);
        comboB_kernel<<<BATCH, 512, 0, stream>>>(
            Ahd, Bhd, b_pre, mu, stdv, out1,
            tie_cnt, cand_col, cand_val, xch, xcl, wT, b_enc, 0);
        auxb_kernel<<<dim3(NDEAD / 32, D_MODEL / 32), 256, 0, stream>>>(w_dec, dead_idx, Bhd);
        wdec2bf_kernel<<<(int)(((size_t)D_HIDDEN * D_MODEL) / (256 * 8)), 256, 0, stream>>>(w_dec, wd16);
        mm256_kernel<1><<<(BATCH / 256) * (D_MODEL / 256), 512, 0, stream>>>(
            Ahd, Bhd, NDEAD, BATCH / 256, b_pre, mu, stdv, out1, (long)D_MODEL);
    }
    decode_fin_kernel<<<BATCH, 256, 0, stream>>>(
        sure_cnt, tie_cnt, cand_col, cand_val, topk_idx, topk_val,
        wd16, b_pre, mu, stdv, out0);
}

// Round 16
// 1991.008 us; speedup vs baseline: 1.0013x; 1.0013x over previous
//
#include <hip/hip_runtime.h>
#include <math.h>

#define D_MODEL  4096
#define D_HIDDEN 32768
#define BATCH    2048
#define KSEL     128
#define NDEAD    2048
#define TIECAP   256

#define NB_SEL 2048
#define NB_AG  2048
#define NB_AB  8192
#define NB_WD  8192
#define NB_MM  128            // aux mm256 blocks inside comboB
#define NB_WPREP 16384        // (D_MODEL/128) * (D_HIDDEN/64)

typedef short s16x8 __attribute__((ext_vector_type(8)));
typedef float f32x4 __attribute__((ext_vector_type(4)));

// -------------------- helpers --------------------
__device__ __forceinline__ unsigned int fkey(float f) {
    unsigned int u = __float_as_uint(f);
    return (u & 0x80000000u) ? ~u : (u | 0x80000000u);
}
__device__ __forceinline__ unsigned short f2bf(float f) {  // RTNE
    unsigned int u = __float_as_uint(f);
    u += 0x7FFFu + ((u >> 16) & 1u);
    return (unsigned short)(u >> 16);
}
__device__ __forceinline__ float bf2f(unsigned short h) {
    return __uint_as_float(((unsigned int)h) << 16);
}
// per-16-bit-lane order-preserving key transform (packed pair)
__device__ __forceinline__ unsigned int key16x2(unsigned int u) {
    const unsigned int s = (u >> 15) & 0x10001u;
    const unsigned int mask = s * 0xFFFFu;
    return (u ^ mask) | (~mask & 0x80008000u);
}
__device__ __forceinline__ float unkey16(unsigned int k) {  // 16-bit key -> float
    const unsigned int u = (k & 0x8000u) ? (k & 0x7FFFu) : (~k & 0xFFFFu);
    return __uint_as_float(u << 16);
}
__device__ __forceinline__ void async_copy16(void* lds_dst, const void* gsrc) {
    __builtin_amdgcn_global_load_lds(
        (const __attribute__((address_space(1))) unsigned int*)gsrc,
        (__attribute__((address_space(3))) unsigned int*)lds_dst,
        16, 0, 0);
}

// ==== prepw: [rows 0..BATCH-1: LN+Ahp+Dekker | BATCH: dead scan | rest: wprep] ====
__global__ __launch_bounds__(256) void prepw_kernel(
    const float* __restrict__ x, const float* __restrict__ b_pre,
    double* __restrict__ mu, double* __restrict__ stdv, double* __restrict__ sinv,
    unsigned short* __restrict__ Ahp, float* __restrict__ xch, float* __restrict__ xcl,
    const unsigned char* __restrict__ mask8, int* __restrict__ dead_idx,
    int* __restrict__ dead_cnt, const int* __restrict__ num_dead_in,
    float* __restrict__ out_last,
    const float* __restrict__ w_enc, unsigned short* __restrict__ Bhp,
    float* __restrict__ wT, const int do_w)
{
    const int b = blockIdx.x;
    const int tid = threadIdx.x;
    __shared__ double red[4];
    __shared__ double sh_mu, sh_si;
    __shared__ float tt[64][129];     // 33 KB transpose buffer

    if (b > BATCH) {
        // ---------------- wprep tile: 128k x 64n ----------------
        const int wb = b - (BATCH + 1);
        const int bk0 = (wb & 31) * 128;        // D_MODEL/128 = 32 (x fastest)
        const int bn0 = (wb >> 5) * 64;
        const int n0 = (tid & 15) * 4;
#pragma unroll
        for (int it = 0; it < 8; ++it) {
            const int k = it * 16 + (tid >> 4);
            const float4 v = *(const float4*)(w_enc + (size_t)(bk0 + k) * D_HIDDEN + bn0 + n0);
            tt[n0 + 0][k] = v.x; tt[n0 + 1][k] = v.y;
            tt[n0 + 2][k] = v.z; tt[n0 + 3][k] = v.w;
        }
        __syncthreads();
        const int n = tid >> 2;
        const int k0 = (tid & 3) * 32;
        unsigned short* bp = Bhp + (size_t)(bn0 + n) * D_MODEL + bk0 + k0;
        float* wp = wT + (size_t)(bn0 + n) * D_MODEL + bk0 + k0;
#pragma unroll
        for (int j = 0; j < 32; j += 8) {
            float f[8];
#pragma unroll
            for (int e = 0; e < 8; ++e) f[e] = tt[n][k0 + j + e];
            uint4 ob;
            ob.x = (unsigned)f2bf(f[0]) | ((unsigned)f2bf(f[1]) << 16);
            ob.y = (unsigned)f2bf(f[2]) | ((unsigned)f2bf(f[3]) << 16);
            ob.z = (unsigned)f2bf(f[4]) | ((unsigned)f2bf(f[5]) << 16);
            ob.w = (unsigned)f2bf(f[6]) | ((unsigned)f2bf(f[7]) << 16);
            *(uint4*)(bp + j) = ob;
            if (do_w) {
                *(float4*)(wp + j)     = make_float4(f[0], f[1], f[2], f[3]);
                *(float4*)(wp + j + 4) = make_float4(f[4], f[5], f[6], f[7]);
            }
        }
        return;
    }
    if (b == BATCH) {
        // ---------------- dead-mask scan (wave 0) ----------------
        if (tid >= 64) return;
        const int lane = tid;
        int c = 0;
        for (int j = lane; j < D_HIDDEN; j += 64) c += (mask8[j] != 0);
#pragma unroll
        for (int off = 32; off > 0; off >>= 1) c += __shfl_down(c, off, 64);
        const int total_u8 = __shfl(c, 0, 64);
        const bool u8mode = (total_u8 == NDEAD);
        const int* mask32 = (const int*)mask8;
        int cnt = 0;
        for (int base = 0; base < D_HIDDEN; base += 64) {
            const int j = base + lane;
            const bool d = u8mode ? (mask8[j] != 0) : (mask32[j] != 0);
            const unsigned long long bm = __ballot(d);
            const int pre = __popcll(bm & ((1ull << lane) - 1ull));
            if (d && (cnt + pre) < NDEAD) dead_idx[cnt + pre] = j;
            cnt += __popcll(bm);
        }
        const int cc = cnt > NDEAD ? NDEAD : cnt;
        if (lane == 0) {
            *dead_cnt = cc;
            *out_last = (float)(*num_dead_in);
        }
        for (int t = cc + lane; t < NDEAD; t += 64) dead_idx[t] = 0;
        return;
    }
    // ---------------- prep row (identical math) ----------------
    const int row = b;
    const float* xr = x + (size_t)row * D_MODEL;
    float xv[16];
#pragma unroll
    for (int i = 0; i < 16; ++i) xv[i] = xr[tid + 256 * i];
    double s = 0.0;
#pragma unroll
    for (int i = 0; i < 16; ++i) s += (double)xv[i];
    const int lane = tid & 63, wid = tid >> 6;
#pragma unroll
    for (int off = 32; off > 0; off >>= 1) s += __shfl_down(s, off, 64);
    if (lane == 0) red[wid] = s;
    __syncthreads();
    if (tid == 0) sh_mu = (red[0] + red[1] + red[2] + red[3]) / (double)D_MODEL;
    __syncthreads();
    const double m = sh_mu;
    double s2 = 0.0;
#pragma unroll
    for (int i = 0; i < 16; ++i) { double d = (double)xv[i] - m; s2 += d * d; }
#pragma unroll
    for (int off = 32; off > 0; off >>= 1) s2 += __shfl_down(s2, off, 64);
    __syncthreads();
    if (lane == 0) red[wid] = s2;
    __syncthreads();
    if (tid == 0) {
        double var = (red[0] + red[1] + red[2] + red[3]) / (double)(D_MODEL - 1);
        double sd = sqrt(var);
        mu[row] = m;
        stdv[row] = sd;
        const double si = 1.0 / (sd + 1e-5);
        sinv[row] = si;
        sh_si = si;
    }
    __syncthreads();
    const double si = sh_si;
#pragma unroll
    for (int i = 0; i < 4; ++i) {
        const int j = (i * 256 + tid) * 4;
        const float4 x4 = *(const float4*)(xr + j);
        const float4 bp = *(const float4*)(b_pre + j);
        float vf[4], hi[4], lo[4];
        const float xe[4] = {x4.x, x4.y, x4.z, x4.w};
        const float be[4] = {bp.x, bp.y, bp.z, bp.w};
#pragma unroll
        for (int e = 0; e < 4; ++e) {
            const double t = ((double)xe[e] - m) * si;
            vf[e] = (float)t - be[e];
            const double a = t - (double)be[e];
            hi[e] = (float)a;
            lo[e] = (float)(a - (double)hi[e]);
        }
        uint2 hw;
        hw.x = (unsigned)f2bf(vf[0]) | ((unsigned)f2bf(vf[1]) << 16);
        hw.y = (unsigned)f2bf(vf[2]) | ((unsigned)f2bf(vf[3]) << 16);
        *(uint2*)(Ahp + (size_t)row * D_MODEL + j) = hw;
        *(float4*)(xch + (size_t)row * D_MODEL + j) = make_float4(hi[0], hi[1], hi[2], hi[3]);
        *(float4*)(xcl + (size_t)row * D_MODEL + j) = make_float4(lo[0], lo[1], lo[2], lo[3]);
    }
}

// -------------------- bsplit (fallback) --------------------
__global__ __launch_bounds__(256) void bsplit_kernel(
    const float* __restrict__ w_enc, unsigned short* __restrict__ Bhp)
{
    __shared__ float t[32][33];
    const int bk = blockIdx.x * 32;
    const int bn = blockIdx.y * 32;
    const int tid = threadIdx.x;
    const int lr = tid >> 3, lc4 = (tid & 7) * 4;
    const float4 v = *(const float4*)(w_enc + (size_t)(bk + lr) * D_HIDDEN + bn + lc4);
    t[lr][lc4 + 0] = v.x; t[lr][lc4 + 1] = v.y; t[lr][lc4 + 2] = v.z; t[lr][lc4 + 3] = v.w;
    __syncthreads();
    float o[4];
#pragma unroll
    for (int j = 0; j < 4; ++j) o[j] = t[lc4 + j][lr];
    uint2 hw;
    hw.x = (unsigned)f2bf(o[0]) | ((unsigned)f2bf(o[1]) << 16);
    hw.y = (unsigned)f2bf(o[2]) | ((unsigned)f2bf(o[3]) << 16);
    *(uint2*)(Bhp + (size_t)(bn + lr) * D_MODEL + bk + lc4) = hw;
}

// -------------------- wencT (fallback) --------------------
__global__ __launch_bounds__(256) void wencT_kernel(
    const float* __restrict__ w_enc, float* __restrict__ wT)
{
    __shared__ float t[32][33];
    const int bk = blockIdx.x * 32;
    const int bn = blockIdx.y * 32;
    const int tid = threadIdx.x;
    const int lr = tid >> 3, lc4 = (tid & 7) * 4;
    const float4 v = *(const float4*)(w_enc + (size_t)(bk + lr) * D_HIDDEN + bn + lc4);
    t[lr][lc4 + 0] = v.x; t[lr][lc4 + 1] = v.y; t[lr][lc4 + 2] = v.z; t[lr][lc4 + 3] = v.w;
    __syncthreads();
    const int j = tid >> 3, i4 = (tid & 7) * 4;
    float4 o;
    o.x = t[i4 + 0][j]; o.y = t[i4 + 1][j]; o.z = t[i4 + 2][j]; o.w = t[i4 + 3][j];
    *(float4*)(wT + (size_t)(bn + j) * D_MODEL + bk + i4) = o;
}

// ======== 256x256 bf16 MFMA GEMM, BK=64, 8 waves, 4-phase/K-tile, half-tile pipe ====
// Hoisted ds_reads: all 12 fragment reads of a half issue right after the
// half-boundary barrier; a2's LDS latency hides under q1's MFMA cluster.
// MFMA operand/order unchanged -> bitwise-identical output.
template<int EPI>
__global__ __launch_bounds__(512) void mm256_kernel(
    const unsigned short* __restrict__ A, const unsigned short* __restrict__ B,
    const int kdim, const int ntiles_x,
    const float* __restrict__ bias_n,
    const double* __restrict__ muv, const double* __restrict__ stdvv,
    void* __restrict__ outp, const long ostride)
{
    __shared__ unsigned short lds[2 * 4 * 8192];   // 128 KB: 2 bufs x 4 subplanes
    const int tid = threadIdx.x;
    const int lane = tid & 63, wid = tid >> 6;     // 8 waves
    const int cpx = gridDim.x >> 3;                // XCD swizzle (grid % 8 == 0)
    const int orig = blockIdx.x;
    const int wg = (orig & 7) * cpx + (orig >> 3);
    const int m0 = (wg % ntiles_x) * 256;
    const int n0 = (wg / ntiles_x) * 256;
    const int wm = (wid >> 2) * 128;               // 2 M-halves
    const int wn = (wid & 3) * 64;                 // 4 N-quarters
    const int fr = lane & 15, kq = lane >> 4;
    const int swr = (fr >> 1) & 3;                 // read-side quad XOR
    const int qg = (lane & 3) ^ ((lane >> 3) & 3); // write-side source quad
    const int qo = (kq ^ swr) * 8;

    f32x4 acc[8][4];
#pragma unroll
    for (int i = 0; i < 8; ++i)
#pragma unroll
        for (int j = 0; j < 4; ++j) acc[i][j] = (f32x4){0.f, 0.f, 0.f, 0.f};

    const unsigned short* sH0[4];
    int dH0[4];
#pragma unroll
    for (int j = 0; j < 4; ++j) {
        const int g = wid * 4 + j;
        const int is_b = g >> 4;
        const int sr = g & 15;
        const unsigned short* gp = is_b ? B : A;
        const int t0 = is_b ? n0 : m0;
        sH0[j] = gp + (size_t)(t0 + sr * 16 + (lane >> 2)) * kdim + qg * 8;
        dH0[j] = (is_b ? 2 : 0) * 8192 + sr * 512;
    }

    const int NT = kdim >> 6;
#pragma unroll
    for (int j = 0; j < 4; ++j) async_copy16(lds + dH0[j], sH0[j]);
#pragma unroll
    for (int j = 0; j < 4; ++j) async_copy16(lds + 8192 + dH0[j], sH0[j] + 32);
    if (NT > 1) {
#pragma unroll
        for (int j = 0; j < 4; ++j) async_copy16(lds + 32768 + dH0[j], sH0[j] + 64);
    }

    for (int t = 0; t < NT; ++t) {
        const int cur = t & 1;
        unsigned short* bb = (unsigned short*)lds + cur * 32768;
        unsigned short* nb = (unsigned short*)lds + (cur ^ 1) * 32768;
        const int k1 = (t + 1) << 6;
        const int k2 = (t + 2) << 6;

        // ======== kk0 half: wait H0(t) ========
        if (t < NT - 1) { asm volatile("s_waitcnt vmcnt(8)" ::: "memory"); }
        else            { asm volatile("s_waitcnt vmcnt(4)" ::: "memory"); }
        asm volatile("s_barrier" ::: "memory");
        __builtin_amdgcn_sched_barrier(0);
        {
            if (t + 1 < NT) {
                async_copy16(nb + 8192 + dH0[0], sH0[0] + k1 + 32);
                async_copy16(nb + 8192 + dH0[1], sH0[1] + k1 + 32);
            }
            s16x8 a[4], a2[4], b[4];
#pragma unroll
            for (int mi = 0; mi < 4; ++mi) {
                a[mi]  = *(const s16x8*)(bb + (wm + mi * 16 + fr) * 32 + qo);
                a2[mi] = *(const s16x8*)(bb + (wm + (mi + 4) * 16 + fr) * 32 + qo);
            }
#pragma unroll
            for (int ni = 0; ni < 4; ++ni)
                b[ni] = *(const s16x8*)(bb + 2 * 8192 + (wn + ni * 16 + fr) * 32 + qo);
            __builtin_amdgcn_s_setprio(1);
#pragma unroll
            for (int mi = 0; mi < 4; ++mi)
#pragma unroll
                for (int ni = 0; ni < 4; ++ni)
                    acc[mi][ni] = __builtin_amdgcn_mfma_f32_16x16x32_bf16(a[mi], b[ni], acc[mi][ni], 0, 0, 0);
            __builtin_amdgcn_s_setprio(0);
            asm volatile("s_barrier" ::: "memory");
            __builtin_amdgcn_sched_barrier(0);
            if (t + 1 < NT) {
                async_copy16(nb + 8192 + dH0[2], sH0[2] + k1 + 32);
                async_copy16(nb + 8192 + dH0[3], sH0[3] + k1 + 32);
            }
            __builtin_amdgcn_s_setprio(1);
#pragma unroll
            for (int mi = 0; mi < 4; ++mi)
#pragma unroll
                for (int ni = 0; ni < 4; ++ni)
                    acc[mi + 4][ni] = __builtin_amdgcn_mfma_f32_16x16x32_bf16(a2[mi], b[ni], acc[mi + 4][ni], 0, 0, 0);
            __builtin_amdgcn_s_setprio(0);
        }
        // ======== kk1 half: wait H1(t) ========
        if (t < NT - 1) { asm volatile("s_waitcnt vmcnt(8)" ::: "memory"); }
        else            { asm volatile("s_waitcnt vmcnt(0)" ::: "memory"); }
        asm volatile("s_barrier" ::: "memory");
        __builtin_amdgcn_sched_barrier(0);
        {
            if (t + 2 < NT) {
                async_copy16(bb + dH0[0], sH0[0] + k2);
                async_copy16(bb + dH0[1], sH0[1] + k2);
            }
            s16x8 a[4], a2[4], b[4];
#pragma unroll
            for (int mi = 0; mi < 4; ++mi) {
                a[mi]  = *(const s16x8*)(bb + 8192 + (wm + mi * 16 + fr) * 32 + qo);
                a2[mi] = *(const s16x8*)(bb + 8192 + (wm + (mi + 4) * 16 + fr) * 32 + qo);
            }
#pragma unroll
            for (int ni = 0; ni < 4; ++ni)
                b[ni] = *(const s16x8*)(bb + 3 * 8192 + (wn + ni * 16 + fr) * 32 + qo);
            __builtin_amdgcn_s_setprio(1);
#pragma unroll
            for (int mi = 0; mi < 4; ++mi)
#pragma unroll
                for (int ni = 0; ni < 4; ++ni)
                    acc[mi][ni] = __builtin_amdgcn_mfma_f32_16x16x32_bf16(a[mi], b[ni], acc[mi][ni], 0, 0, 0);
            __builtin_amdgcn_s_setprio(0);
            asm volatile("s_barrier" ::: "memory");
            __builtin_amdgcn_sched_barrier(0);
            if (t + 2 < NT) {
                async_copy16(bb + dH0[2], sH0[2] + k2);
                async_copy16(bb + dH0[3], sH0[3] + k2);
            }
            __builtin_amdgcn_s_setprio(1);
#pragma unroll
            for (int mi = 0; mi < 4; ++mi)
#pragma unroll
                for (int ni = 0; ni < 4; ++ni)
                    acc[mi + 4][ni] = __builtin_amdgcn_mfma_f32_16x16x32_bf16(a2[mi], b[ni], acc[mi + 4][ni], 0, 0, 0);
            __builtin_amdgcn_s_setprio(0);
        }
    }

#pragma unroll
    for (int ni = 0; ni < 4; ++ni) {
        const int col = n0 + wn + ni * 16 + fr;
        const float be = bias_n[col];
#pragma unroll
        for (int mi = 0; mi < 8; ++mi) {
            const int rb = m0 + wm + mi * 16 + kq * 4;
            if (EPI == 0) {
                unsigned short* O = (unsigned short*)outp;
#pragma unroll
                for (int r = 0; r < 4; ++r)
                    O[(size_t)(rb + r) * ostride + col] = f2bf(acc[mi][ni][r] + be);
            } else {
                float* O = (float*)outp;
#pragma unroll
                for (int r = 0; r < 4; ++r) {
                    const int m = rb + r;
                    O[(size_t)m * ostride + col] =
                        (acc[mi][ni][r] + be) * (float)stdvv[m] + (float)muv[m];
                }
            }
        }
    }
}

// ======= comboA: [sel | auxg | auxb(nb_ab) | wdec2bf(nb_wd)] in one launch =======
__global__ __launch_bounds__(256) void comboA_kernel(
    const unsigned short* __restrict__ p16,
    int* __restrict__ topk_idx, float* __restrict__ topk_val,
    int* __restrict__ sure_cnt, int* __restrict__ tie_cnt, int* __restrict__ cand_col,
    const int* __restrict__ dead_idx, const int* __restrict__ dead_cnt,
    unsigned short* __restrict__ Ahd,
    const float* __restrict__ w_dec, unsigned short* __restrict__ Bhd,
    unsigned short* __restrict__ wd16,
    const int nb_ab, const int nb_wd)
{
    const int b = blockIdx.x;
    const int tid = threadIdx.x;
    __shared__ float tsm[32][33];
    __shared__ int red[4];
    __shared__ int sh_sel, sh_tie;

    if (b < NB_SEL) {
        const int row = b;
        const int lane = tid & 63, wid = tid >> 6;
        const unsigned short* pr = p16 + (size_t)row * D_HIDDEN;
        uint4 kr[16];
#pragma unroll
        for (int i = 0; i < 16; ++i) {
            uint4 w = *(const uint4*)(pr + (i * 256 + tid) * 8);
            w.x = key16x2(w.x); w.y = key16x2(w.y); w.z = key16x2(w.z); w.w = key16x2(w.w);
            kr[i] = w;
        }
        if (tid == 0) { sh_sel = 0; sh_tie = 0; }
        unsigned int lo = 0, hi = 65535;
        while (lo < hi) {
            const unsigned int mid = (lo + hi) >> 1;
            int c = 0;
#pragma unroll
            for (int i = 0; i < 16; ++i) {
                const unsigned int u[4] = {kr[i].x, kr[i].y, kr[i].z, kr[i].w};
#pragma unroll
                for (int e = 0; e < 4; ++e) {
                    c += (int)((u[e] & 0xFFFFu) > mid);
                    c += (int)((u[e] >> 16) > mid);
                }
            }
#pragma unroll
            for (int off = 32; off > 0; off >>= 1) c += __shfl_down(c, off, 64);
            if (lane == 0) red[wid] = c;
            __syncthreads();
            const int total = red[0] + red[1] + red[2] + red[3];
            if (total < KSEL) hi = mid; else lo = mid + 1;
            __syncthreads();
        }
        const unsigned int K16 = lo;
        const float vc = unkey16(K16);
        const float DLT = 1.3e-2f;
        const float sureT = vc + 2.f * DLT;
        const float candT = vc - 2.f * DLT;
        const unsigned int sK = fkey(sureT) >> 16;
        const unsigned int cK = fkey(candT) >> 16;
        int* oidx = topk_idx + row * KSEL;
        float* oval = topk_val + row * KSEL;
        int* cc = cand_col + row * TIECAP;
#pragma unroll
        for (int i = 0; i < 16; ++i) {
            const int j0 = (i * 256 + tid) * 8;
            const unsigned int u[4] = {kr[i].x, kr[i].y, kr[i].z, kr[i].w};
#pragma unroll
            for (int e = 0; e < 8; ++e) {
                const unsigned int k = (e & 1) ? (u[e >> 1] >> 16) : (u[e >> 1] & 0xFFFFu);
                if (k < cK) continue;
                const float v = unkey16(k);
                if (k > sK && v > sureT) {
                    const int pos = atomicAdd(&sh_sel, 1);
                    oidx[pos] = j0 + e;
                    oval[pos] = v > 0.f ? v : 0.f;
                } else if (v >= candT) {
                    const int t = atomicAdd(&sh_tie, 1);
                    if (t < TIECAP) cc[t] = j0 + e;
                }
            }
        }
        __syncthreads();
        if (tid == 0) {
            sure_cnt[row] = sh_sel;
            tie_cnt[row] = sh_tie > TIECAP ? TIECAP : sh_tie;
        }
        return;
    }
    if (b < NB_SEL + NB_AG) {
        const int r = b - NB_SEL;
        const int dc = *dead_cnt;
#pragma unroll
        for (int i = 0; i < 8; ++i) {
            const int c = i * 256 + tid;
            unsigned short v = 0;
            if (c < dc) {
                const unsigned short u = p16[(size_t)r * D_HIDDEN + dead_idx[c]];
                v = (u & 0x8000u) ? (unsigned short)0 : u;
            }
            Ahd[(size_t)r * NDEAD + c] = v;
        }
        return;
    }
    if (b < NB_SEL + NB_AG + nb_ab) {
        const int idx = b - (NB_SEL + NB_AG);
        const int k0 = (idx & 63) * 32;
        const int n0 = (idx >> 6) * 32;
        const int i = tid >> 3, j4 = (tid & 7) * 4;
        const int srow = dead_idx[k0 + i];
        const float4 v = *(const float4*)(w_dec + (size_t)srow * D_MODEL + n0 + j4);
        tsm[i][j4 + 0] = v.x; tsm[i][j4 + 1] = v.y; tsm[i][j4 + 2] = v.z; tsm[i][j4 + 3] = v.w;
        __syncthreads();
        const int j = tid >> 3, i4 = (tid & 7) * 4;
        uint2 hw;
        hw.x = (unsigned)f2bf(tsm[i4 + 0][j]) | ((unsigned)f2bf(tsm[i4 + 1][j]) << 16);
        hw.y = (unsigned)f2bf(tsm[i4 + 2][j]) | ((unsigned)f2bf(tsm[i4 + 3][j]) << 16);
        *(uint2*)(Bhd + (size_t)(n0 + j) * NDEAD + k0 + i4) = hw;
        return;
    }
    {
        const int bb = b - (NB_SEL + NB_AG + nb_ab);
        (void)nb_wd;
        const size_t base0 = (size_t)bb * 16384;
#pragma unroll
        for (int it = 0; it < 8; ++it) {
            const size_t off = base0 + (size_t)it * 2048 + (size_t)tid * 8;
            const float4 a = *(const float4*)(w_dec + off);
            const float4 c = *(const float4*)(w_dec + off + 4);
            uint4 o;
            o.x = (unsigned)f2bf(a.x) | ((unsigned)f2bf(a.y) << 16);
            o.y = (unsigned)f2bf(a.z) | ((unsigned)f2bf(a.w) << 16);
            o.z = (unsigned)f2bf(c.x) | ((unsigned)f2bf(c.y) << 16);
            o.w = (unsigned)f2bf(c.z) | ((unsigned)f2bf(c.w) << 16);
            *(uint4*)(wd16 + off) = o;
        }
        return;
    }
}

// ---------- standalone auxb + wdec2bf (fallback ordering) ----------
__global__ __launch_bounds__(256) void auxb_kernel(
    const float* __restrict__ w_dec, const int* __restrict__ dead_idx,
    unsigned short* __restrict__ Bhd)
{
    __shared__ float t[32][33];
    const int k0 = blockIdx.x * 32;
    const int n0 = blockIdx.y * 32;
    const int tid = threadIdx.x;
    const int i = tid >> 3, j4 = (tid & 7) * 4;
    const int srow = dead_idx[k0 + i];
    const float4 v = *(const float4*)(w_dec + (size_t)srow * D_MODEL + n0 + j4);
    t[i][j4 + 0] = v.x; t[i][j4 + 1] = v.y; t[i][j4 + 2] = v.z; t[i][j4 + 3] = v.w;
    __syncthreads();
    const int j = tid >> 3, i4 = (tid & 7) * 4;
    uint2 hw;
    hw.x = (unsigned)f2bf(t[i4 + 0][j]) | ((unsigned)f2bf(t[i4 + 1][j]) << 16);
    hw.y = (unsigned)f2bf(t[i4 + 2][j]) | ((unsigned)f2bf(t[i4 + 3][j]) << 16);
    *(uint2*)(Bhd + (size_t)(n0 + j) * NDEAD + k0 + i4) = hw;
}

__global__ __launch_bounds__(256) void wdec2bf_kernel(
    const float* __restrict__ w_dec, unsigned short* __restrict__ wd16)
{
    const size_t gid = (size_t)blockIdx.x * 256 + threadIdx.x;
    const size_t base = gid * 8;
    const float4 a = *(const float4*)(w_dec + base);
    const float4 b = *(const float4*)(w_dec + base + 4);
    uint4 o;
    o.x = (unsigned)f2bf(a.x) | ((unsigned)f2bf(a.y) << 16);
    o.y = (unsigned)f2bf(a.z) | ((unsigned)f2bf(a.w) << 16);
    o.z = (unsigned)f2bf(b.x) | ((unsigned)f2bf(b.y) << 16);
    o.w = (unsigned)f2bf(b.z) | ((unsigned)f2bf(b.w) << 16);
    *(uint4*)(wd16 + base) = o;
}

// ======= comboB: [aux mm256 (nb_mm blocks) | row-refine (BATCH blocks)] =========
__global__ __launch_bounds__(512) void comboB_kernel(
    const unsigned short* __restrict__ A, const unsigned short* __restrict__ B,
    const float* __restrict__ bias_n,
    const double* __restrict__ muv, const double* __restrict__ stdvv,
    float* __restrict__ out1,
    const int* __restrict__ tie_cnt, const int* __restrict__ cand_col,
    double* __restrict__ cand_val,
    const float* __restrict__ xch, const float* __restrict__ xcl,
    const float* __restrict__ wT, const float* __restrict__ b_enc,
    const int nb_mm)
{
    __shared__ unsigned short lds[2 * 4 * 8192];   // 128 KB (refine uses first 32 KB)
    const int tid = threadIdx.x;
    const int lane = tid & 63, wid = tid >> 6;

    if (blockIdx.x >= nb_mm) {
        // ---------------- row refine ----------------
        const int row = blockIdx.x - nb_mm;
        const int T = tie_cnt[row];
        if (T == 0) return;
        float* shh = (float*)lds;
        float* shl = shh + D_MODEL;
        const float* hr = xch + (size_t)row * D_MODEL;
        const float* lr2 = xcl + (size_t)row * D_MODEL;
        {
            const int o = tid * 8;
            *(float4*)(shh + o)     = *(const float4*)(hr + o);
            *(float4*)(shh + o + 4) = *(const float4*)(hr + o + 4);
            *(float4*)(shl + o)     = *(const float4*)(lr2 + o);
            *(float4*)(shl + o + 4) = *(const float4*)(lr2 + o + 4);
        }
        __syncthreads();
        for (int slot = wid; slot < T; slot += 8) {
            const int col = cand_col[row * TIECAP + slot];
            const float* wr = wT + (size_t)col * D_MODEL;
            double s0 = 0.0, s1 = 0.0;
            for (int k = lane * 4; k < D_MODEL; k += 512) {
                {
                    const float4 h = *(const float4*)(shh + k);
                    const float4 l = *(const float4*)(shl + k);
                    const float4 w4 = *(const float4*)(wr + k);
                    s0 += ((double)h.x + (double)l.x) * (double)w4.x;
                    s0 += ((double)h.y + (double)l.y) * (double)w4.y;
                    s0 += ((double)h.z + (double)l.z) * (double)w4.z;
                    s0 += ((double)h.w + (double)l.w) * (double)w4.w;
                }
                {
                    const int k2 = k + 256;
                    const float4 h = *(const float4*)(shh + k2);
                    const float4 l = *(const float4*)(shl + k2);
                    const float4 w4 = *(const float4*)(wr + k2);
                    s1 += ((double)h.x + (double)l.x) * (double)w4.x;
                    s1 += ((double)h.y + (double)l.y) * (double)w4.y;
                    s1 += ((double)h.z + (double)l.z) * (double)w4.z;
                    s1 += ((double)h.w + (double)l.w) * (double)w4.w;
                }
            }
            double s = s0 + s1;
#pragma unroll
            for (int off = 32; off > 0; off >>= 1) s += __shfl_down(s, off, 64);
            if (lane == 0) cand_val[row * TIECAP + slot] = s + (double)b_enc[col];
        }
        return;
    }

    // ---------------- aux mm256 (EPI=1), K = NDEAD ----------------
    const int kdim = NDEAD;
    const int ntiles_x = BATCH / 256;
    const int cpx = nb_mm >> 3;
    const int orig = blockIdx.x;
    const int wg = (orig & 7) * cpx + (orig >> 3);
    const int m0 = (wg % ntiles_x) * 256;
    const int n0 = (wg / ntiles_x) * 256;
    const int wm = (wid >> 2) * 128;
    const int wn = (wid & 3) * 64;
    const int fr = lane & 15, kq = lane >> 4;
    const int swr = (fr >> 1) & 3;
    const int qg = (lane & 3) ^ ((lane >> 3) & 3);
    const int qo = (kq ^ swr) * 8;

    f32x4 acc[8][4];
#pragma unroll
    for (int i = 0; i < 8; ++i)
#pragma unroll
        for (int j = 0; j < 4; ++j) acc[i][j] = (f32x4){0.f, 0.f, 0.f, 0.f};

    const unsigned short* sH0[4];
    int dH0[4];
#pragma unroll
    for (int j = 0; j < 4; ++j) {
        const int g = wid * 4 + j;
        const int is_b = g >> 4;
        const int sr = g & 15;
        const unsigned short* gp = is_b ? B : A;
        const int t0 = is_b ? n0 : m0;
        sH0[j] = gp + (size_t)(t0 + sr * 16 + (lane >> 2)) * kdim + qg * 8;
        dH0[j] = (is_b ? 2 : 0) * 8192 + sr * 512;
    }

    const int NT = kdim >> 6;
#pragma unroll
    for (int j = 0; j < 4; ++j) async_copy16(lds + dH0[j], sH0[j]);
#pragma unroll
    for (int j = 0; j < 4; ++j) async_copy16(lds + 8192 + dH0[j], sH0[j] + 32);
    if (NT > 1) {
#pragma unroll
        for (int j = 0; j < 4; ++j) async_copy16(lds + 32768 + dH0[j], sH0[j] + 64);
    }

    for (int t = 0; t < NT; ++t) {
        const int cur = t & 1;
        unsigned short* bb = (unsigned short*)lds + cur * 32768;
        unsigned short* nb = (unsigned short*)lds + (cur ^ 1) * 32768;
        const int k1 = (t + 1) << 6;
        const int k2 = (t + 2) << 6;

        if (t < NT - 1) { asm volatile("s_waitcnt vmcnt(8)" ::: "memory"); }
        else            { asm volatile("s_waitcnt vmcnt(4)" ::: "memory"); }
        asm volatile("s_barrier" ::: "memory");
        __builtin_amdgcn_sched_barrier(0);
        {
            if (t + 1 < NT) {
                async_copy16(nb + 8192 + dH0[0], sH0[0] + k1 + 32);
                async_copy16(nb + 8192 + dH0[1], sH0[1] + k1 + 32);
            }
            s16x8 a[4], a2[4], b[4];
#pragma unroll
            for (int mi = 0; mi < 4; ++mi) {
                a[mi]  = *(const s16x8*)(bb + (wm + mi * 16 + fr) * 32 + qo);
                a2[mi] = *(const s16x8*)(bb + (wm + (mi + 4) * 16 + fr) * 32 + qo);
            }
#pragma unroll
            for (int ni = 0; ni < 4; ++ni)
                b[ni] = *(const s16x8*)(bb + 2 * 8192 + (wn + ni * 16 + fr) * 32 + qo);
            __builtin_amdgcn_s_setprio(1);
#pragma unroll
            for (int mi = 0; mi < 4; ++mi)
#pragma unroll
                for (int ni = 0; ni < 4; ++ni)
                    acc[mi][ni] = __builtin_amdgcn_mfma_f32_16x16x32_bf16(a[mi], b[ni], acc[mi][ni], 0, 0, 0);
            __builtin_amdgcn_s_setprio(0);
            asm volatile("s_barrier" ::: "memory");
            __builtin_amdgcn_sched_barrier(0);
            if (t + 1 < NT) {
                async_copy16(nb + 8192 + dH0[2], sH0[2] + k1 + 32);
                async_copy16(nb + 8192 + dH0[3], sH0[3] + k1 + 32);
            }
            __builtin_amdgcn_s_setprio(1);
#pragma unroll
            for (int mi = 0; mi < 4; ++mi)
#pragma unroll
                for (int ni = 0; ni < 4; ++ni)
                    acc[mi + 4][ni] = __builtin_amdgcn_mfma_f32_16x16x32_bf16(a2[mi], b[ni], acc[mi + 4][ni], 0, 0, 0);
            __builtin_amdgcn_s_setprio(0);
        }
        if (t < NT - 1) { asm volatile("s_waitcnt vmcnt(8)" ::: "memory"); }
        else            { asm volatile("s_waitcnt vmcnt(0)" ::: "memory"); }
        asm volatile("s_barrier" ::: "memory");
        __builtin_amdgcn_sched_barrier(0);
        {
            if (t + 2 < NT) {
                async_copy16(bb + dH0[0], sH0[0] + k2);
                async_copy16(bb + dH0[1], sH0[1] + k2);
            }
            s16x8 a[4], a2[4], b[4];
#pragma unroll
            for (int mi = 0; mi < 4; ++mi) {
                a[mi]  = *(const s16x8*)(bb + 8192 + (wm + mi * 16 + fr) * 32 + qo);
                a2[mi] = *(const s16x8*)(bb + 8192 + (wm + (mi + 4) * 16 + fr) * 32 + qo);
            }
#pragma unroll
            for (int ni = 0; ni < 4; ++ni)
                b[ni] = *(const s16x8*)(bb + 3 * 8192 + (wn + ni * 16 + fr) * 32 + qo);
            __builtin_amdgcn_s_setprio(1);
#pragma unroll
            for (int mi = 0; mi < 4; ++mi)
#pragma unroll
                for (int ni = 0; ni < 4; ++ni)
                    acc[mi][ni] = __builtin_amdgcn_mfma_f32_16x16x32_bf16(a[mi], b[ni], acc[mi][ni], 0, 0, 0);
            __builtin_amdgcn_s_setprio(0);
            asm volatile("s_barrier" ::: "memory");
            __builtin_amdgcn_sched_barrier(0);
            if (t + 2 < NT) {
                async_copy16(bb + dH0[2], sH0[2] + k2);
                async_copy16(bb + dH0[3], sH0[3] + k2);
            }
            __builtin_amdgcn_s_setprio(1);
#pragma unroll
            for (int mi = 0; mi < 4; ++mi)
#pragma unroll
                for (int ni = 0; ni < 4; ++ni)
                    acc[mi + 4][ni] = __builtin_amdgcn_mfma_f32_16x16x32_bf16(a2[mi], b[ni], acc[mi + 4][ni], 0, 0, 0);
            __builtin_amdgcn_s_setprio(0);
        }
    }

#pragma unroll
    for (int ni = 0; ni < 4; ++ni) {
        const int col = n0 + wn + ni * 16 + fr;
        const float be = bias_n[col];
#pragma unroll
        for (int mi = 0; mi < 8; ++mi) {
            const int rb = m0 + wm + mi * 16 + kq * 4;
#pragma unroll
            for (int r = 0; r < 4; ++r) {
                const int m = rb + r;
                out1[(size_t)m * D_MODEL + col] =
                    (acc[mi][ni][r] + be) * (float)stdvv[m] + (float)muv[m];
            }
        }
    }
}

// ---------- decode_fin: per-row candidate rank (fin) fused with sparse decode ----
__global__ __launch_bounds__(256) void decode_fin_kernel(
    const int* __restrict__ sure_cnt, const int* __restrict__ tie_cnt,
    const int* __restrict__ cand_col, const double* __restrict__ cand_val,
    const int* __restrict__ topk_idx, const float* __restrict__ topk_val,
    const unsigned short* __restrict__ wd16, const float* __restrict__ b_pre,
    const double* __restrict__ mu, const double* __restrict__ stdv,
    float* __restrict__ out0)
{
    const int row = blockIdx.x;
    const int tid = threadIdx.x;
    __shared__ double vals[TIECAP];
    __shared__ int cols[TIECAP];
    __shared__ int sidx[KSEL];
    __shared__ float sval[KSEL];
    const int G = sure_cnt[row];
    const int T = tie_cnt[row];
    const int R = KSEL - G;
    if (tid < T) {
        vals[tid] = cand_val[row * TIECAP + tid];
        cols[tid] = cand_col[row * TIECAP + tid];
    }
    if (tid < G) {
        sidx[tid] = topk_idx[row * KSEL + tid];
        sval[tid] = topk_val[row * KSEL + tid];
    }
    __syncthreads();
    if (tid < T) {
        const double v = vals[tid];
        const int c = cols[tid];
        int rank = 0;
        for (int u = 0; u < T; ++u) {
            const double vu = vals[u];
            rank += (int)((vu > v) || (vu == v && cols[u] < c));
        }
        if (rank < R) {
            sidx[G + rank] = c;
            sval[G + rank] = v > 0.0 ? (float)v : 0.f;
        }
    }
    const int take = R < T ? R : T;
    if (tid >= take && tid < R) {
        sidx[G + tid] = (T > 0) ? cols[0] : 0;
        sval[G + tid] = 0.f;
    }
    __syncthreads();
    float acc[16];
#pragma unroll
    for (int i = 0; i < 16; ++i) acc[i] = 0.f;
    const int dbase = tid * 16;
    for (int k = 0; k < KSEL; ++k) {
        const float v = sval[k];
        if (v == 0.f) continue;
        const uint4* wr = (const uint4*)(wd16 + (size_t)sidx[k] * D_MODEL + dbase);
        const uint4 w0 = wr[0], w1 = wr[1];
        const unsigned int u[8] = {w0.x, w0.y, w0.z, w0.w, w1.x, w1.y, w1.z, w1.w};
#pragma unroll
        for (int i = 0; i < 8; ++i) {
            acc[2 * i]     += v * __uint_as_float(u[i] << 16);
            acc[2 * i + 1] += v * __uint_as_float(u[i] & 0xFFFF0000u);
        }
    }
    const float st = (float)stdv[row];
    const float mm = (float)mu[row];
    float* o = out0 + (size_t)row * D_MODEL + dbase;
#pragma unroll
    for (int i = 0; i < 16; ++i) {
        o[i] = (acc[i] + b_pre[dbase + i]) * st + mm;
    }
}

// -------------------- launch --------------------
extern "C" void kernel_launch(void* const* d_in, const int* in_sizes, int n_in,
                              void* d_out, int out_size, void* d_ws, size_t ws_size,
                              hipStream_t stream)
{
    (void)in_sizes; (void)n_in; (void)out_size;
    const float* x      = (const float*)d_in[0];
    const float* w_enc  = (const float*)d_in[1];
    const float* w_dec  = (const float*)d_in[2];
    const float* b_enc  = (const float*)d_in[3];
    const float* b_pre  = (const float*)d_in[4];
    const unsigned char* dead_mask = (const unsigned char*)d_in[5];
    const int* num_dead = (const int*)d_in[6];
    float* out = (float*)d_out;

    char* base = (char*)d_ws;
    char* w = base;
    auto alloc = [&](size_t bytes) -> char* {
        char* p = w;
        w += (bytes + 255) & ~(size_t)255;
        return p;
    };
    unsigned short* p16 = (unsigned short*)alloc((size_t)BATCH * D_HIDDEN * 2); // 128 MB
    double* mu       = (double*)alloc((size_t)BATCH * 8);
    double* stdv     = (double*)alloc((size_t)BATCH * 8);
    double* sinv     = (double*)alloc((size_t)BATCH * 8);
    int* topk_idx    = (int*)alloc((size_t)BATCH * KSEL * 4);
    float* topk_val  = (float*)alloc((size_t)BATCH * KSEL * 4);
    int* dead_idx    = (int*)alloc((size_t)NDEAD * 4);
    int* dead_cnt    = (int*)alloc(256);
    int* sure_cnt    = (int*)alloc((size_t)BATCH * 4);
    int* tie_cnt     = (int*)alloc((size_t)BATCH * 4);
    int* cand_col    = (int*)alloc((size_t)BATCH * TIECAP * 4);      // 2 MB
    double* cand_val = (double*)alloc((size_t)BATCH * TIECAP * 8);   // 4 MB
    float* xch       = (float*)alloc((size_t)BATCH * D_MODEL * 4);   // 32 MB
    float* xcl       = (float*)alloc((size_t)BATCH * D_MODEL * 4);   // 32 MB
    unsigned short* Ahp = (unsigned short*)alloc((size_t)BATCH * D_MODEL * 2);    // 16 MB
    char* region     = alloc((size_t)D_HIDDEN * D_MODEL * 4);                     // 512 MB
    float* wT_big    = (float*)alloc((size_t)D_HIDDEN * D_MODEL * 4);             // 512 MB
    const size_t need_big = (size_t)(w - base);
    const bool bigws = (ws_size >= need_big);

    // time-multiplexed region:
    unsigned short* Bhp = (unsigned short*)region;                 // 256 MB, enc phase
    float* wT_small = (float*)region;                              // 512 MB (fallback, after enc)
    unsigned short* wd16 = (unsigned short*)region;                // 256 MB, decode phase
    unsigned short* Bhd  = (unsigned short*)(region + (size_t)D_HIDDEN * D_MODEL * 2); // 16 MB
    unsigned short* Ahd  = Ahp;                                    // 8 MB (Ahp dead after enc)
    float* wT = bigws ? wT_big : wT_small;

    float* out0 = out;                                   // recons
    float* out1 = out + (size_t)BATCH * D_MODEL;         // auxk
    float* out_last = out + (size_t)2 * BATCH * D_MODEL; // num_dead

    if (bigws) {
        prepw_kernel<<<BATCH + 1 + NB_WPREP, 256, 0, stream>>>(
            x, b_pre, mu, stdv, sinv, Ahp, xch, xcl,
            dead_mask, dead_idx, dead_cnt, num_dead, out_last,
            w_enc, Bhp, wT, 1);
        mm256_kernel<0><<<(BATCH / 256) * (D_HIDDEN / 256), 512, 0, stream>>>(
            Ahp, Bhp, D_MODEL, BATCH / 256, b_enc, nullptr, nullptr, p16, (long)D_HIDDEN);
        comboA_kernel<<<NB_SEL + NB_AG + NB_AB + NB_WD, 256, 0, stream>>>(
            p16, topk_idx, topk_val, sure_cnt, tie_cnt, cand_col,
            dead_idx, dead_cnt, Ahd, w_dec, Bhd, wd16, NB_AB, NB_WD);
        comboB_kernel<<<NB_MM + BATCH, 512, 0, stream>>>(
            Ahd, Bhd, b_pre, mu, stdv, out1,
            tie_cnt, cand_col, cand_val, xch, xcl, wT, b_enc, NB_MM);
    } else {
        prepw_kernel<<<BATCH + 1, 256, 0, stream>>>(
            x, b_pre, mu, stdv, sinv, Ahp, xch, xcl,
            dead_mask, dead_idx, dead_cnt, num_dead, out_last,
            w_enc, Bhp, nullptr, 0);
        bsplit_kernel<<<dim3(D_MODEL / 32, D_HIDDEN / 32), 256, 0, stream>>>(w_enc, Bhp);
        mm256_kernel<0><<<(BATCH / 256) * (D_HIDDEN / 256), 512, 0, stream>>>(
            Ahp, Bhp, D_MODEL, BATCH / 256, b_enc, nullptr, nullptr, p16, (long)D_HIDDEN);
        wencT_kernel<<<dim3(D_MODEL / 32, D_HIDDEN / 32), 256, 0, stream>>>(w_enc, wT);
        comboA_kernel<<<NB_SEL + NB_AG, 256, 0, stream>>>(
            p16, topk_idx, topk_val, sure_cnt, tie_cnt, cand_col,
            dead_idx, dead_cnt, Ahd, w_dec, Bhd, wd16, 0, 0);
        comboB_kernel<<<BATCH, 512, 0, stream>>>(
            Ahd, Bhd, b_pre, mu, stdv, out1,
            tie_cnt, cand_col, cand_val, xch, xcl, wT, b_enc, 0);
        auxb_kernel<<<dim3(NDEAD / 32, D_MODEL / 32), 256, 0, stream>>>(w_dec, dead_idx, Bhd);
        wdec2bf_kernel<<<(int)(((size_t)D_HIDDEN * D_MODEL) / (256 * 8)), 256, 0, stream>>>(w_dec, wd16);
        mm256_kernel<1><<<(BATCH / 256) * (D_MODEL / 256), 512, 0, stream>>>(
            Ahd, Bhd, NDEAD, BATCH / 256, b_pre, mu, stdv, out1, (long)D_MODEL);
    }
    decode_fin_kernel<<<BATCH, 256, 0, stream>>>(
        sure_cnt, tie_cnt, cand_col, cand_val, topk_idx, topk_val,
        wd16, b_pre, mu, stdv, out0);
}